// Round 11
// baseline (111.578 us; speedup 1.0000x reference)
//
#include <hip/hip_runtime.h>
#include <hip/hip_bf16.h>

#define BD 4
#define SD 2048
#define DD 512
#define VD 32000
#define NTOK (BD * SD)
#define EPS_L2 1e-12f
#define ROW_BLOCKS (VD / 4)  // one wave per row, 4 waves/block

// ws layout: [ head V int ][ next NTOK int ][ pgw NTOK f32 ]
#define WS_NEXT VD
#define WS_PGW (VD + NTOK)

// K1 (after a 128KB memset of head to 0xFF): build per-vocab token lists,
// stash p[t,gold] (sign encodes pad), zero the loss slot out[0].
__global__ void __launch_bounds__(256)
build_kernel(const int* __restrict__ gold, const int* __restrict__ mask,
             const float* __restrict__ p, int* __restrict__ head,
             int* __restrict__ next, float* __restrict__ pgw,
             float* __restrict__ out) {
    int t = blockIdx.x * 256 + threadIdx.x;
    if (t == 0) out[0] = 0.f;  // loss accumulator
    int g = gold[t];
    next[t] = atomicExch(&head[g], t);
    float pg = p[(size_t)t * VD + g];
    pgw[t] = mask[t] ? -1.f : pg;  // p in [0,1); sign marks pad
}

// K2: one wave per vocab row. Single pass: copy/blend + loss. Loss goes
// straight into out[0] via one atomicAdd per touched row (~7.2K total,
// spread over the kernel — hidden). NO __threadfence (R8: fence storm =
// XCD L2 writeback, 302us). No nontemporal (R7: 9.6x regression).
__global__ void __launch_bounds__(256, 8)
row_kernel(const float* __restrict__ x, const float* __restrict__ cache,
           const int* __restrict__ head, const int* __restrict__ next,
           const float* __restrict__ pgw, float* __restrict__ out) {
    int row = blockIdx.x * 4 + (threadIdx.x >> 6);
    int lane = threadIdx.x & 63;
    int t = head[row];  // start dependent chain early
    const float4* cr = (const float4*)cache + (size_t)row * (DD / 4);
    float4 ca = cr[lane], cb = cr[64 + lane];
    float* o = out + 1 + (size_t)row * DD;
    int b = lane * 4;

    if (t < 0) {  // untouched row: passthrough copy
        o[b + 0] = ca.x; o[b + 1] = ca.y; o[b + 2] = ca.z; o[b + 3] = ca.w;
        o[256 + b + 0] = cb.x; o[256 + b + 1] = cb.y;
        o[256 + b + 2] = cb.z; o[256 + b + 3] = cb.w;
        return;
    }

    float sc = ca.x * ca.x + ca.y * ca.y + ca.z * ca.z + ca.w * ca.w
             + cb.x * cb.x + cb.y * cb.y + cb.z * cb.z + cb.w * cb.w;
    #pragma unroll
    for (int off = 32; off; off >>= 1) sc += __shfl_xor(sc, off, 64);
    float rnc = 1.0f / fmaxf(sqrtf(sc), EPS_L2);

    float4 aa = {0.f, 0.f, 0.f, 0.f}, ab = {0.f, 0.f, 0.f, 0.f};
    float lossAcc = 0.f;
    int cnt = 0;
    while (t >= 0) {
        int tn = next[t];
        float w = pgw[t];  // broadcast; < 0 means padded
        const float4* xr = (const float4*)x + (size_t)t * (DD / 4);
        float4 xa = xr[lane], xb = xr[64 + lane];

        float dot = xa.x * ca.x + xa.y * ca.y + xa.z * ca.z + xa.w * ca.w
                  + xb.x * cb.x + xb.y * cb.y + xb.z * cb.z + xb.w * cb.w;
        float sx = xa.x * xa.x + xa.y * xa.y + xa.z * xa.z + xa.w * xa.w
                 + xb.x * xb.x + xb.y * xb.y + xb.z * xb.z + xb.w * xb.w;
        #pragma unroll
        for (int off = 32; off; off >>= 1) {
            dot += __shfl_xor(dot, off, 64);
            sx += __shfl_xor(sx, off, 64);
        }
        cnt++;  // counts include padded tokens (ref semantics)
        if (w >= 0.f) {
            float rnx = 1.0f / fmaxf(sqrtf(sx), EPS_L2);
            lossAcc += 2.f - 2.f * dot * rnx * rnc;
            aa.x += w * xa.x; aa.y += w * xa.y;
            aa.z += w * xa.z; aa.w += w * xa.w;
            ab.x += w * xb.x; ab.y += w * xb.y;
            ab.z += w * xb.z; ab.w += w * xb.w;
        }
        t = tn;
    }

    float m = 0.1f / (float)cnt;
    o[b + 0] = 0.9f * ca.x + m * aa.x;
    o[b + 1] = 0.9f * ca.y + m * aa.y;
    o[b + 2] = 0.9f * ca.z + m * aa.z;
    o[b + 3] = 0.9f * ca.w + m * aa.w;
    o[256 + b + 0] = 0.9f * cb.x + m * ab.x;
    o[256 + b + 1] = 0.9f * cb.y + m * ab.y;
    o[256 + b + 2] = 0.9f * cb.z + m * ab.z;
    o[256 + b + 3] = 0.9f * cb.w + m * ab.w;

    if (lane == 0 && lossAcc != 0.f) atomicAdd(out, lossAcc);
}

extern "C" void kernel_launch(void* const* d_in, const int* in_sizes, int n_in,
                              void* d_out, int out_size, void* d_ws, size_t ws_size,
                              hipStream_t stream) {
    const float* x = (const float*)d_in[0];
    const float* p = (const float*)d_in[1];
    const int* gold = (const int*)d_in[2];
    const int* mask = (const int*)d_in[3];
    const float* cache = (const float*)d_in[4];
    float* out = (float*)d_out;
    int* head = (int*)d_ws;
    int* next = head + WS_NEXT;
    float* pgw = (float*)d_ws + WS_PGW;

    hipMemsetAsync(head, 0xFF, sizeof(int) * VD, stream);  // head = -1
    build_kernel<<<NTOK / 256, 256, 0, stream>>>(gold, mask, p, head, next,
                                                 pgw, out);
    row_kernel<<<ROW_BLOCKS, 256, 0, stream>>>(x, cache, head, next, pgw, out);
}

// Round 12
// 38.228 us; speedup vs baseline: 2.9187x; 2.9187x over previous
//
#include <hip/hip_runtime.h>
#include <hip/hip_bf16.h>

#define BD 4
#define SD 2048
#define DD 512
#define VD 32000
#define NTOK (BD * SD)
#define EPS_L2 1e-12f
#define ROW_BLOCKS (VD / 4)  // one wave per row, 4 waves/block

// 16B vector with 4B alignment: global dwordx4 only needs dword alignment,
// so stores to the out+1-shifted rows stay single instructions.
typedef float f32x4u __attribute__((ext_vector_type(4), aligned(4)));

// ws layout: [ head V int ][ next NTOK int ][ pgw NTOK f32 ][ lossPart 256 f32 ]
#define WS_NEXT VD
#define WS_PGW (VD + NTOK)
#define WS_LOSSP (VD + 2 * NTOK)

// K1 (after a 128KB memset of head to 0xFF): build per-vocab token lists,
// stash p[t,gold] (sign encodes pad), zero loss partials.
__global__ void __launch_bounds__(256)
build_kernel(const int* __restrict__ gold, const int* __restrict__ mask,
             const float* __restrict__ p, int* __restrict__ head,
             int* __restrict__ next, float* __restrict__ pgw,
             float* __restrict__ lossPart) {
    int t = blockIdx.x * 256 + threadIdx.x;
    if (blockIdx.x == 0) lossPart[threadIdx.x] = 0.f;
    int g = gold[t];
    next[t] = atomicExch(&head[g], t);
    float pg = p[(size_t)t * VD + g];
    pgw[t] = mask[t] ? -1.f : pg;  // p in [0,1); sign marks pad
}

// K2: one wave per vocab row. Stores are 2x dwordx4 per lane (4B-aligned ok).
// Loss -> lossPart[256] (spread; R11: single-address atomics cost +73us).
// NO __threadfence (R8), no nontemporal (R7).
__global__ void __launch_bounds__(256, 8)
row_kernel(const float* __restrict__ x, const float* __restrict__ cache,
           const int* __restrict__ head, const int* __restrict__ next,
           const float* __restrict__ pgw, float* __restrict__ out,
           float* __restrict__ lossPart) {
    int row = blockIdx.x * 4 + (threadIdx.x >> 6);
    int lane = threadIdx.x & 63;
    int t = head[row];  // start dependent chain early
    const float4* cr = (const float4*)cache + (size_t)row * (DD / 4);
    float4 ca = cr[lane], cb = cr[64 + lane];
    float* o = out + 1 + (size_t)row * DD;
    int b = lane * 4;

    if (t < 0) {  // untouched row: passthrough copy
        f32x4u va = {ca.x, ca.y, ca.z, ca.w};
        f32x4u vb = {cb.x, cb.y, cb.z, cb.w};
        *(f32x4u*)(o + b) = va;
        *(f32x4u*)(o + 256 + b) = vb;
        return;
    }

    float sc = ca.x * ca.x + ca.y * ca.y + ca.z * ca.z + ca.w * ca.w
             + cb.x * cb.x + cb.y * cb.y + cb.z * cb.z + cb.w * cb.w;
    #pragma unroll
    for (int off = 32; off; off >>= 1) sc += __shfl_xor(sc, off, 64);
    float rnc = 1.0f / fmaxf(sqrtf(sc), EPS_L2);

    float4 aa = {0.f, 0.f, 0.f, 0.f}, ab = {0.f, 0.f, 0.f, 0.f};
    float lossAcc = 0.f;
    int cnt = 0;
    while (t >= 0) {
        int tn = next[t];
        float w = pgw[t];  // broadcast; < 0 means padded
        const float4* xr = (const float4*)x + (size_t)t * (DD / 4);
        float4 xa = xr[lane], xb = xr[64 + lane];

        float dot = xa.x * ca.x + xa.y * ca.y + xa.z * ca.z + xa.w * ca.w
                  + xb.x * cb.x + xb.y * cb.y + xb.z * cb.z + xb.w * cb.w;
        float sx = xa.x * xa.x + xa.y * xa.y + xa.z * xa.z + xa.w * xa.w
                 + xb.x * xb.x + xb.y * xb.y + xb.z * xb.z + xb.w * xb.w;
        #pragma unroll
        for (int off = 32; off; off >>= 1) {
            dot += __shfl_xor(dot, off, 64);
            sx += __shfl_xor(sx, off, 64);
        }
        cnt++;  // counts include padded tokens (ref semantics)
        if (w >= 0.f) {
            float rnx = 1.0f / fmaxf(sqrtf(sx), EPS_L2);
            lossAcc += 2.f - 2.f * dot * rnx * rnc;
            aa.x += w * xa.x; aa.y += w * xa.y;
            aa.z += w * xa.z; aa.w += w * xa.w;
            ab.x += w * xb.x; ab.y += w * xb.y;
            ab.z += w * xb.z; ab.w += w * xb.w;
        }
        t = tn;
    }

    float m = 0.1f / (float)cnt;
    f32x4u va = {0.9f * ca.x + m * aa.x, 0.9f * ca.y + m * aa.y,
                 0.9f * ca.z + m * aa.z, 0.9f * ca.w + m * aa.w};
    f32x4u vb = {0.9f * cb.x + m * ab.x, 0.9f * cb.y + m * ab.y,
                 0.9f * cb.z + m * ab.z, 0.9f * cb.w + m * ab.w};
    *(f32x4u*)(o + b) = va;
    *(f32x4u*)(o + 256 + b) = vb;

    if (lane == 0 && lossAcc != 0.f) {
        int wv = (blockIdx.x * 256 + threadIdx.x) >> 6;
        atomicAdd(&lossPart[wv & 255], lossAcc);
    }
}

// K3: reduce 256 loss partials -> out[0].
__global__ void __launch_bounds__(256)
loss_reduce_kernel(const float* __restrict__ lossPart, float* __restrict__ out) {
    __shared__ float sm[4];
    float a = lossPart[threadIdx.x];
    #pragma unroll
    for (int off = 32; off; off >>= 1) a += __shfl_xor(a, off, 64);
    if ((threadIdx.x & 63) == 0) sm[threadIdx.x >> 6] = a;
    __syncthreads();
    if (threadIdx.x == 0) out[0] = sm[0] + sm[1] + sm[2] + sm[3];
}

extern "C" void kernel_launch(void* const* d_in, const int* in_sizes, int n_in,
                              void* d_out, int out_size, void* d_ws, size_t ws_size,
                              hipStream_t stream) {
    const float* x = (const float*)d_in[0];
    const float* p = (const float*)d_in[1];
    const int* gold = (const int*)d_in[2];
    const int* mask = (const int*)d_in[3];
    const float* cache = (const float*)d_in[4];
    float* out = (float*)d_out;
    int* head = (int*)d_ws;
    int* next = head + WS_NEXT;
    float* pgw = (float*)d_ws + WS_PGW;
    float* lossPart = (float*)d_ws + WS_LOSSP;

    hipMemsetAsync(head, 0xFF, sizeof(int) * VD, stream);  // head = -1
    build_kernel<<<NTOK / 256, 256, 0, stream>>>(gold, mask, p, head, next,
                                                 pgw, lossPart);
    row_kernel<<<ROW_BLOCKS, 256, 0, stream>>>(x, cache, head, next, pgw, out,
                                               lossPart);
    loss_reduce_kernel<<<1, 256, 0, stream>>>(lossPart, out);
}